// Round 4
// baseline (522.704 us; speedup 1.0000x reference)
//
#include <hip/hip_runtime.h>
#include <math.h>

#define NN 4096
#define PP 10
#define DD 17
#define DIM 300
#define NPD (NN * PP * DD)          // 696,320 entries
#define NENT NPD
#define NROWS 99999                 // emb2 rows (VOCAB-1)
#define RPB 32                      // rows per bucket
#define NB ((NROWS + RPB - 1) / RPB)   // 3125 buckets
#define NBPAD 3136                  // 64 lanes * 49 bins, padded for scan
#define BPL 49                      // bins per lane in scan

// ---------------- sort pipeline ----------------

__global__ void zero_kernel(unsigned* cnt) {
    for (int i = threadIdx.x; i < NBPAD; i += 256) cnt[i] = 0;
}

__global__ void hist_kernel(const int* __restrict__ paths, unsigned* __restrict__ cnt) {
    const int e = blockIdx.x * 256 + threadIdx.x;      // grid sized exactly
    const unsigned b = ((unsigned)paths[e]) >> 5;
    atomicAdd(&cnt[b], 1u);
}

__global__ void scan_kernel(const unsigned* __restrict__ cnt,
                            unsigned* __restrict__ off, unsigned* __restrict__ cur) {
    const int lane = threadIdx.x;                      // 64 threads, 1 wave
    unsigned local[BPL];
    unsigned s = 0;
    const int base = lane * BPL;
    #pragma unroll
    for (int j = 0; j < BPL; ++j) { local[j] = s; s += cnt[base + j]; }
    // wave-wide exclusive scan of per-lane totals
    unsigned t = s;
    #pragma unroll
    for (int o = 1; o < 64; o <<= 1) {
        unsigned u = __shfl_up(t, o);
        if (lane >= o) t += u;
    }
    const unsigned excl = t - s;
    #pragma unroll
    for (int j = 0; j < BPL; ++j) {
        const unsigned v = excl + local[j];
        off[base + j] = v;
        cur[base + j] = v;
    }
}

__global__ void scatter_kernel(const int* __restrict__ paths,
                               unsigned* __restrict__ cur,
                               unsigned long long* __restrict__ rec) {
    const int e = blockIdx.x * 256 + threadIdx.x;
    const int row = paths[e];
    const unsigned b = ((unsigned)row) >> 5;
    const unsigned pos = atomicAdd(&cur[b], 1u);
    rec[pos] = (((unsigned long long)(unsigned)row) << 32) | (unsigned)e;
}

// ---------------- compute ----------------

struct Ent { int e; int rl; bool v; float4 a0, a1, a2; };

__device__ __forceinline__ void load_entry(
    int t, unsigned start, unsigned end, int wv, int h, int j, long long r0,
    const unsigned long long* __restrict__ rec,
    const int* __restrict__ word_idx,
    const float* __restrict__ emb1, Ent& E)
{
    const int i = (int)start + 2 * (wv + t * 4) + h;
    E.v = i < (int)end;
    const int ic = E.v ? i : (int)start;               // bucket non-empty here
    const unsigned long long r = rec[ic];
    E.e = (int)(r & 0xffffffffULL);
    const int row = (int)(r >> 32);
    E.rl = row - (int)r0;
    const int n = E.e / 170;                           // e -> sample index
    const int wr = word_idx[n];
    const float4* pp = (const float4*)(emb1 + (long long)wr * DIM);
    E.a0 = pp[j];
    E.a1 = pp[j + 32];
    E.a2 = (j < 11) ? pp[j + 64] : make_float4(0.f, 0.f, 0.f, 0.f);
}

__global__ __launch_bounds__(256, 4) void compute_kernel(
    const int* __restrict__ word_idx,
    const int* __restrict__ labels,
    const float* __restrict__ emb1,
    const float* __restrict__ emb2,
    const unsigned* __restrict__ off,
    const unsigned long long* __restrict__ rec,
    float* __restrict__ out, float* __restrict__ target)
{
    __shared__ float lds[RPB * DIM];                   // 38,400 B -> 4 blocks/CU
    const int b = blockIdx.x;
    const int tid = threadIdx.x;
    const long long r0 = (long long)b * RPB;
    const int nr = (NROWS - r0 < RPB) ? (int)(NROWS - r0) : RPB;

    // stage this bucket's contiguous emb2 slice -> LDS (streamed, coalesced)
    {
        const float4* src4 = (const float4*)(emb2 + r0 * DIM);
        float4* l4 = (float4*)lds;
        const int nf4 = nr * (DIM / 4);                // 75 float4 per row
        for (int t = tid; t < nf4; t += 256) l4[t] = src4[t];
    }
    __syncthreads();

    const int lane = tid & 63;
    const int wv = tid >> 6;                           // wave 0..3
    const int h = lane >> 5;                           // half-wave: one entry each
    const int j = lane & 31;

    const unsigned start = off[b];
    const unsigned end = off[b + 1];                   // b+1 <= 3125 < NBPAD
    const int cnt = (int)(end - start);
    const int mywork = cnt - 2 * wv;
    const int niter = (mywork > 0) ? ((mywork + 7) >> 3) : 0;
    if (niter == 0) return;

    Ent C;
    load_entry(0, start, end, wv, h, j, r0, rec, word_idx, emb1, C);

    for (int t = 0; t < niter; ++t) {
        Ent Nx;
        if (t + 1 < niter)                             // depth-1 prefetch
            load_entry(t + 1, start, end, wv, h, j, r0, rec, word_idx, emb1, Nx);

        const float4* r4 = (const float4*)(lds + C.rl * DIM);
        const float4 c0 = r4[j];
        const float4 c1 = r4[j + 32];
        float acc = C.a0.x * c0.x + C.a0.y * c0.y + C.a0.z * c0.z + C.a0.w * c0.w
                  + C.a1.x * c1.x + C.a1.y * c1.y + C.a1.z * c1.z + C.a1.w * c1.w;
        if (j < 11) {
            const float4 c2 = r4[j + 64];
            acc += C.a2.x * c2.x + C.a2.y * c2.y + C.a2.z * c2.z + C.a2.w * c2.w;
        }
        #pragma unroll
        for (int o = 16; o > 0; o >>= 1)               // stays within the half
            acc += __shfl_xor(acc, o);

        if (C.v && j == 0) {                           // lanes 0 and 32 write
            const float o_ = 1.0f / (1.0f + expf(-acc));
            out[C.e] = o_;
            const int m = (o_ >= 0.5f) ? 1 : 0;
            const int lb = labels[C.e];
            target[C.e] = (m == lb) ? 1.0f : 0.0f;
        }
        if (t + 1 < niter) C = Nx;
    }
}

// ---------------- fallback (round-1 structure) ----------------

__global__ __launch_bounds__(256) void hs_fwd_fallback(
    const int* __restrict__ word_idx, const int* __restrict__ paths,
    const int* __restrict__ labels, const float* __restrict__ emb1,
    const float* __restrict__ emb2, float* __restrict__ out, float* __restrict__ target)
{
    const int wave = (int)((blockIdx.x * blockDim.x + threadIdx.x) >> 6);
    const int lane = (int)(threadIdx.x & 63);
    if (wave >= NN * PP) return;
    const int n = wave / PP;
    const float* e1 = emb1 + (long long)word_idx[n] * DIM;
    const float pr0 = e1[lane];
    const float pr1 = e1[lane + 64];
    const float pr2 = e1[lane + 128];
    const float pr3 = e1[lane + 192];
    const float pr4 = (lane < DIM - 256) ? e1[lane + 256] : 0.0f;
    const long long base = (long long)wave * DD;
    const int my_path  = (lane < DD) ? paths[base + lane]  : 0;
    const int my_label = (lane < DD) ? labels[base + lane] : 0;
    float my_logit = 0.0f;
    #pragma unroll
    for (int k = 0; k < DD; ++k) {
        const int row = __shfl(my_path, k);
        const float* e2 = emb2 + (long long)row * DIM;
        float acc = pr0 * e2[lane] + pr1 * e2[lane + 64] + pr2 * e2[lane + 128]
                  + pr3 * e2[lane + 192];
        if (lane < DIM - 256) acc += pr4 * e2[lane + 256];
        #pragma unroll
        for (int o = 32; o > 0; o >>= 1) acc += __shfl_xor(acc, o);
        if (lane == k) my_logit = acc;
    }
    if (lane < DD) {
        const float o = 1.0f / (1.0f + expf(-my_logit));
        out[base + lane] = o;
        const int mask = (o >= 0.5f) ? 1 : 0;
        target[base + lane] = (mask == my_label) ? 1.0f : 0.0f;
    }
}

// ---------------- launch ----------------

extern "C" void kernel_launch(void* const* d_in, const int* in_sizes, int n_in,
                              void* d_out, int out_size, void* d_ws, size_t ws_size,
                              hipStream_t stream) {
    const int*   word_idx = (const int*)d_in[0];
    const int*   paths    = (const int*)d_in[1];
    const int*   labels   = (const int*)d_in[2];
    const float* emb1     = (const float*)d_in[3];
    const float* emb2     = (const float*)d_in[4];

    float* out    = (float*)d_out;
    float* target = (float*)d_out + NPD;

    // workspace layout: cnt[3136] | off[3136] | cur[3136] | rec[NENT] (u64)
    const size_t rec_off = (size_t)NBPAD * 3 * sizeof(unsigned);   // 37,632 (8-aligned)
    const size_t need = rec_off + (size_t)NENT * sizeof(unsigned long long);

    if (ws_size < need) {
        const int blocks = (NN * PP + 3) / 4;
        hs_fwd_fallback<<<blocks, 256, 0, stream>>>(word_idx, paths, labels, emb1, emb2, out, target);
        return;
    }

    unsigned* cnt = (unsigned*)d_ws;
    unsigned* off = cnt + NBPAD;
    unsigned* cur = off + NBPAD;
    unsigned long long* rec = (unsigned long long*)((char*)d_ws + rec_off);

    zero_kernel<<<1, 256, 0, stream>>>(cnt);
    hist_kernel<<<NENT / 256, 256, 0, stream>>>(paths, cnt);
    scan_kernel<<<1, 64, 0, stream>>>(cnt, off, cur);
    scatter_kernel<<<NENT / 256, 256, 0, stream>>>(paths, cur, rec);
    compute_kernel<<<NB, 256, 0, stream>>>(word_idx, labels, emb1, emb2, off, rec, out, target);
}

// Round 5
// 423.018 us; speedup vs baseline: 1.2357x; 1.2357x over previous
//
#include <hip/hip_runtime.h>
#include <hip/hip_fp16.h>
#include <math.h>

#define NN 4096
#define PP 10
#define DD 17
#define DIM 300
#define NPD (NN * PP * DD)                    // 696,320
#define NROWS 99999                           // emb2 rows
#define TAB_HALFS (29999700LL)                // NROWS * DIM
#define TAB_F4 (7499925LL)                    // TAB_HALFS / 4
#define DELTA 0.004f                          // 4x worst-case fp16 logit error

// ws layout: [0,8) counter | [8, 8+NPD*4) refine list | tab (fp16, 64B-aligned)
#define TAB_OFF 2785344ULL
#define WS_NEED (TAB_OFF + TAB_HALFS * 2ULL)  // ~62.8 MB

// ---- convert emb2 fp32 -> fp16 table (streamed), zero the refine counter ----
__global__ __launch_bounds__(256) void convert_kernel(
    const float* __restrict__ src, ushort* __restrict__ dst, unsigned* __restrict__ counter)
{
    if (blockIdx.x == 0 && threadIdx.x == 0) *counter = 0;
    const long long stride = (long long)gridDim.x * blockDim.x;
    const float4* s4 = (const float4*)src;
    uint2* d2 = (uint2*)dst;
    for (long long i = blockIdx.x * (long long)blockDim.x + threadIdx.x; i < TAB_F4; i += stride) {
        const float4 f = s4[i];
        const __half2 h0 = __floats2half2_rn(f.x, f.y);
        const __half2 h1 = __floats2half2_rn(f.z, f.w);
        uint2 u;
        u.x = *(const unsigned*)&h0;
        u.y = *(const unsigned*)&h1;
        d2[i] = u;
    }
}

// ---- main pass: round-1 structure, fp16 emb2 gathers (600 B/row) ----
__global__ __launch_bounds__(256) void main_fp16(
    const int* __restrict__ word_idx, const int* __restrict__ paths,
    const int* __restrict__ labels, const float* __restrict__ emb1,
    const ushort* __restrict__ tab, float* __restrict__ out, float* __restrict__ target,
    unsigned* __restrict__ counter, unsigned* __restrict__ list)
{
    const int wave = (int)((blockIdx.x * blockDim.x + threadIdx.x) >> 6);
    const int lane = (int)(threadIdx.x & 63);
    if (wave >= NN * PP) return;
    const int n = wave / PP;

    // proj[n]: lane owns elements [4*lane, 4*lane+4) and [256+4*lane, ...) for lane<11
    const float4* p4 = (const float4*)(emb1 + (long long)word_idx[n] * DIM);
    const float4 p0 = p4[lane];
    const float4 p1 = (lane < 11) ? p4[lane + 64] : make_float4(0.f, 0.f, 0.f, 0.f);

    const long long base = (long long)wave * DD;
    const int my_path  = (lane < DD) ? paths[base + lane]  : 0;
    const int my_label = (lane < DD) ? labels[base + lane] : 0;

    float my_logit = 0.0f;
    #pragma unroll
    for (int k = 0; k < DD; ++k) {
        const int row = __shfl(my_path, k);
        const uint2* q2 = (const uint2*)(tab + (long long)row * DIM);
        const uint2 a = q2[lane];                       // halves [4*lane, 4*lane+4)
        const float2 f0 = __half22float2(*(const __half2*)&a.x);
        const float2 f1 = __half22float2(*(const __half2*)&a.y);
        float acc = p0.x * f0.x + p0.y * f0.y + p0.z * f1.x + p0.w * f1.y;
        if (lane < 11) {
            const uint2 b = q2[lane + 64];              // halves [256+4*lane, ...)
            const float2 g0 = __half22float2(*(const __half2*)&b.x);
            const float2 g1 = __half22float2(*(const __half2*)&b.y);
            acc += p1.x * g0.x + p1.y * g0.y + p1.z * g1.x + p1.w * g1.y;
        }
        #pragma unroll
        for (int off = 32; off > 0; off >>= 1)
            acc += __shfl_xor(acc, off);
        if (lane == k) my_logit = acc;
    }

    if (lane < DD) {
        const float o = 1.0f / (1.0f + expf(-my_logit));
        out[base + lane] = o;
        const int mask = (o >= 0.5f) ? 1 : 0;
        target[base + lane] = (mask == my_label) ? 1.0f : 0.0f;
        if (fabsf(my_logit) < DELTA) {                  // ~1.8% of entries
            const unsigned idx = atomicAdd(counter, 1u);
            list[idx] = (unsigned)(base + lane);
        }
    }
}

// ---- refine: fp32 recompute for near-zero logits (one wave per entry) ----
__global__ __launch_bounds__(256) void refine_kernel(
    const int* __restrict__ word_idx, const int* __restrict__ paths,
    const int* __restrict__ labels, const float* __restrict__ emb1,
    const float* __restrict__ emb2, const unsigned* __restrict__ counter,
    const unsigned* __restrict__ list, float* __restrict__ out, float* __restrict__ target)
{
    const int wid  = (int)((blockIdx.x * blockDim.x + threadIdx.x) >> 6);
    const int lane = (int)(threadIdx.x & 63);
    const int nflag = (int)*counter;
    const int nw = (int)(gridDim.x * (blockDim.x >> 6));
    for (int idx = wid; idx < nflag; idx += nw) {
        const int e = (int)list[idx];
        const int n = e / (PP * DD);
        const float* p = emb1 + (long long)word_idx[n] * DIM;
        const float* h = emb2 + (long long)paths[e] * DIM;
        float acc = p[lane] * h[lane] + p[lane + 64] * h[lane + 64]
                  + p[lane + 128] * h[lane + 128] + p[lane + 192] * h[lane + 192];
        if (lane < DIM - 256) acc += p[lane + 256] * h[lane + 256];
        #pragma unroll
        for (int off = 32; off > 0; off >>= 1)
            acc += __shfl_xor(acc, off);
        if (lane == 0) {
            const float o = 1.0f / (1.0f + expf(-acc));
            out[e] = o;
            const int mask = (o >= 0.5f) ? 1 : 0;
            target[e] = (mask == labels[e]) ? 1.0f : 0.0f;
        }
    }
}

// ---- fallback (round-1 fp32, known-good 142 us) ----
__global__ __launch_bounds__(256) void hs_fwd_fallback(
    const int* __restrict__ word_idx, const int* __restrict__ paths,
    const int* __restrict__ labels, const float* __restrict__ emb1,
    const float* __restrict__ emb2, float* __restrict__ out, float* __restrict__ target)
{
    const int wave = (int)((blockIdx.x * blockDim.x + threadIdx.x) >> 6);
    const int lane = (int)(threadIdx.x & 63);
    if (wave >= NN * PP) return;
    const int n = wave / PP;
    const float* e1 = emb1 + (long long)word_idx[n] * DIM;
    const float pr0 = e1[lane];
    const float pr1 = e1[lane + 64];
    const float pr2 = e1[lane + 128];
    const float pr3 = e1[lane + 192];
    const float pr4 = (lane < DIM - 256) ? e1[lane + 256] : 0.0f;
    const long long base = (long long)wave * DD;
    const int my_path  = (lane < DD) ? paths[base + lane]  : 0;
    const int my_label = (lane < DD) ? labels[base + lane] : 0;
    float my_logit = 0.0f;
    #pragma unroll
    for (int k = 0; k < DD; ++k) {
        const int row = __shfl(my_path, k);
        const float* e2 = emb2 + (long long)row * DIM;
        float acc = pr0 * e2[lane] + pr1 * e2[lane + 64] + pr2 * e2[lane + 128]
                  + pr3 * e2[lane + 192];
        if (lane < DIM - 256) acc += pr4 * e2[lane + 256];
        #pragma unroll
        for (int o = 32; o > 0; o >>= 1) acc += __shfl_xor(acc, o);
        if (lane == k) my_logit = acc;
    }
    if (lane < DD) {
        const float o = 1.0f / (1.0f + expf(-my_logit));
        out[base + lane] = o;
        const int mask = (o >= 0.5f) ? 1 : 0;
        target[base + lane] = (mask == my_label) ? 1.0f : 0.0f;
    }
}

extern "C" void kernel_launch(void* const* d_in, const int* in_sizes, int n_in,
                              void* d_out, int out_size, void* d_ws, size_t ws_size,
                              hipStream_t stream) {
    const int*   word_idx = (const int*)d_in[0];
    const int*   paths    = (const int*)d_in[1];
    const int*   labels   = (const int*)d_in[2];
    const float* emb1     = (const float*)d_in[3];
    const float* emb2     = (const float*)d_in[4];

    float* out    = (float*)d_out;
    float* target = (float*)d_out + NPD;

    if (ws_size < WS_NEED) {
        const int blocks = (NN * PP + 3) / 4;
        hs_fwd_fallback<<<blocks, 256, 0, stream>>>(word_idx, paths, labels, emb1, emb2, out, target);
        return;
    }

    unsigned* counter = (unsigned*)d_ws;
    unsigned* list    = counter + 2;                       // offset 8
    ushort*   tab     = (ushort*)((char*)d_ws + TAB_OFF);  // 64B-aligned

    convert_kernel<<<4096, 256, 0, stream>>>(emb2, tab, counter);
    main_fp16<<<(NN * PP + 3) / 4, 256, 0, stream>>>(word_idx, paths, labels, emb1, tab,
                                                     out, target, counter, list);
    refine_kernel<<<256, 256, 0, stream>>>(word_idx, paths, labels, emb1, emb2,
                                           counter, list, out, target);
}